// Round 1
// baseline (295.444 us; speedup 1.0000x reference)
//
#include <hip/hip_runtime.h>

// Problem constants: B=4, C1=128, C2=64, H1=W1=128, H2=W2=256, G1=8, G2=16
// BS1=8 (64/block), BS2=16 (256/block), nb=256 blocks/batch.

// ---- workspace layout (float offsets) ----
#define GAP1_OFF 0         // [4*128]  per-channel means of x1
#define GAP2_OFF 512       // [4*64]   per-channel means of x2
#define WSUM_OFF 768       // [64]     row sums of w_f
#define WF2_OFF  832       // [4*64*64] w_f[o,c]*cw[b,c]
#define POS1_OFF 17216     // [4*256*64]
#define POS2_OFF 82752     // [4*256*256]
#define SPA_OFF  344896    // [4*256*256]
// total 607040 floats = 2.32 MB of d_ws

// ---------------- K1: per-channel means (gap1, gap2) ----------------
__global__ __launch_bounds__(256) void k_gap(const float* __restrict__ x1,
                                             const float* __restrict__ x2,
                                             float* __restrict__ ws) {
  __shared__ float red[4];
  int blk = blockIdx.x, t = threadIdx.x;
  const float4* base;
  int n4; float inv; float* out;
  if (blk < 512) {                 // x1 channels: 4*128
    base = (const float4*)(x1 + (size_t)blk * 16384);
    n4 = 4096; inv = 1.f / 16384.f; out = ws + GAP1_OFF + blk;
  } else {                         // x2 channels: 4*64
    int c = blk - 512;
    base = (const float4*)(x2 + (size_t)c * 65536);
    n4 = 16384; inv = 1.f / 65536.f; out = ws + GAP2_OFF + c;
  }
  float s = 0.f;
  for (int i = t; i < n4; i += 256) { float4 v = base[i]; s += (v.x + v.y) + (v.z + v.w); }
#pragma unroll
  for (int m = 32; m; m >>= 1) s += __shfl_xor(s, m);
  if ((t & 63) == 0) red[t >> 6] = s;
  __syncthreads();
  if (t == 0) *out = (red[0] + red[1] + red[2] + red[3]) * inv;
}

// ---------------- K2: channel-attention weights + fused conv matrix ----------------
__global__ __launch_bounds__(256) void k_small(const float* __restrict__ w_c1,
                                               const float* __restrict__ b_c1,
                                               const float* __restrict__ w_c2,
                                               const float* __restrict__ b_c2,
                                               const float* __restrict__ w_f,
                                               float* __restrict__ ws) {
  __shared__ float cw_s[256];   // [b][channel 0..63]
  int t = threadIdx.x;
  if (t < 32) {
    int b = t >> 3, g = t & 7;
    const float* g1 = ws + GAP1_OFF + (b * 8 + g) * 16;
    const float* g2 = ws + GAP2_OFF + (b * 8 + g) * 8;
    float m1[8], m2[8];
    for (int o = 0; o < 8; ++o) {
      float s = b_c1[o];
      for (int c = 0; c < 16; ++c) s = fmaf(w_c1[o * 16 + c], g1[c], s);
      m1[o] = fmaxf(s, 0.f);
    }
    float ss = 0.f;
    for (int p = 0; p < 8; ++p) {
      float s = b_c2[p];
      for (int c = 0; c < 8; ++c) s = fmaf(w_c2[p * 8 + c], g2[c], s);
      float r = fmaxf(s, 0.f);
      m2[p] = r; ss = fmaf(r, r, ss);
    }
    float lg[8], mx = -1e30f;
    for (int o = 0; o < 8; ++o) { lg[o] = m1[o] * ss; mx = fmaxf(mx, lg[o]); }
    float se = 0.f;
    for (int o = 0; o < 8; ++o) { lg[o] = __expf(lg[o] - mx); se += lg[o]; }
    float inv = 1.f / se;
    for (int o = 0; o < 8; ++o) cw_s[b * 64 + g * 8 + o] = lg[o] * inv;
  }
  __syncthreads();
  if (t < 64) {
    float s = 0.f;
    for (int c = 0; c < 64; ++c) s += w_f[t * 64 + c];
    ws[WSUM_OFF + t] = s;
  }
  for (int i = t; i < 16384; i += 256) {
    int rem = i & 4095;        // o*64+c  (== w_f flat index)
    int b = i >> 12, c = rem & 63;
    ws[WF2_OFF + i] = w_f[rem] * cw_s[b * 64 + c];
  }
}

// ---------------- K3: pos1 (x1 1x1->1) and pos2 (x2 1x1->1), block-gathered ----------------
__global__ __launch_bounds__(256) void k_pos(const float* __restrict__ x1,
                                             const float* __restrict__ x2,
                                             const float* __restrict__ w_p1,
                                             const float* __restrict__ b_p1,
                                             const float* __restrict__ w_p2,
                                             const float* __restrict__ b_p2,
                                             float* __restrict__ ws) {
  int blk = blockIdx.x, t = threadIdx.x;
  if (blk < 256) {
    int gid = blk * 256 + t;                 // B*128*128 = 65536
    int b = gid >> 14, hw = gid & 16383;
    int h = hw >> 7, w = hw & 127;
    const float* p = x1 + ((size_t)b << 21) + hw;
    float s = b_p1[0];
#pragma unroll 8
    for (int c = 0; c < 128; ++c) s = fmaf(w_p1[c], p[(size_t)c << 14], s);
    int n = ((h >> 3) << 4) + (w >> 3);
    ws[POS1_OFF + ((b * 256 + n) << 6) + ((h & 7) << 3) + (w & 7)] = s;
  } else {
    int gid = (blk - 256) * 256 + t;         // B*256*256 = 262144
    int b = gid >> 16, hw = gid & 65535;
    int h = hw >> 8, w = hw & 255;
    const float* p = x2 + ((size_t)b << 22) + hw;
    float s = b_p2[0];
#pragma unroll 8
    for (int c = 0; c < 64; ++c) s = fmaf(w_p2[c], p[(size_t)c << 16], s);
    int n = ((h >> 4) << 4) + (w >> 4);
    ws[POS2_OFF + ((b * 256 + n) << 8) + ((h & 15) << 4) + (w & 15)] = s;
  }
}

// ---------------- K4: per-block rank-1 spatial attention ----------------
// scores[q,k] = pos2[q]*x1t[k]; softmax over k; weighted[k] = sum_q pos2[q]*aw[q,k]
__global__ __launch_bounds__(256) void k_attn(const float* __restrict__ w_lin,
                                              const float* __restrict__ b_lin,
                                              float* __restrict__ ws) {
  __shared__ float P1[64], V[256], A[256], Sq[256], Mq[256], rmx[4], rmn[4];
  int bn = blockIdx.x, t = threadIdx.x;
  if (t < 64) P1[t] = ws[POS1_OFF + bn * 64 + t];
  float a = ws[POS2_OFF + bn * 256 + t];
  A[t] = a;
  __syncthreads();
  // x1t[t] = w_lin[t,:] . pos1 + b_lin[t]
  float v = b_lin[t];
  const float* wr = w_lin + t * 64;
#pragma unroll
  for (int c = 0; c < 64; ++c) v = fmaf(wr[c], P1[c], v);
  V[t] = v;
  // block-wide max/min of x1t (rank-1 softmax: rowmax = a>0 ? a*vmax : a*vmin)
  float vmax = v, vmin = v;
#pragma unroll
  for (int m = 32; m; m >>= 1) {
    vmax = fmaxf(vmax, __shfl_xor(vmax, m));
    vmin = fminf(vmin, __shfl_xor(vmin, m));
  }
  if ((t & 63) == 0) { rmx[t >> 6] = vmax; rmn[t >> 6] = vmin; }
  __syncthreads();
  vmax = fmaxf(fmaxf(rmx[0], rmx[1]), fmaxf(rmx[2], rmx[3]));
  vmin = fminf(fminf(rmn[0], rmn[1]), fminf(rmn[2], rmn[3]));
  // pass 1: softmax denominator for row q=t
  float m = (a > 0.f) ? a * vmax : a * vmin;
  float den = 0.f;
#pragma unroll 8
  for (int k = 0; k < 256; ++k) den += __expf(fmaf(a, V[k], -m));
  Sq[t] = a / den; Mq[t] = m;
  __syncthreads();
  // pass 2: weighted[k=t] = sum_q (a_q/den_q) * exp(a_q*v_k - m_q)
  float acc = 0.f;
#pragma unroll 8
  for (int q = 0; q < 256; ++q) acc = fmaf(Sq[q], __expf(fmaf(A[q], v, -Mq[q])), acc);
  // raw row-major flatten: spa[b, h=n, w=k]
  ws[SPA_OFF + bn * 256 + t] = acc;
}

// ---------------- K5: fused 1x1 conv (folded cw) + BN + ReLU ----------------
// out[b,o,p] = relu((sum_c wf2[b,o,c]*x2[b,c,p] + spa[b,p]*wsum[o] + b_f[o]) * kbn * gamma[o] + beta[o])
__global__ __launch_bounds__(256) void k_final(const float* __restrict__ x2,
                                               const float* __restrict__ b_f,
                                               const float* __restrict__ gm_,
                                               const float* __restrict__ bt_,
                                               const float* __restrict__ ws,
                                               float* __restrict__ out) {
  __shared__ float M[4096];
  __shared__ float wsum[64], bf[64], gm[64], bt[64];
  int t = threadIdx.x;
  int gid = blockIdx.x * 256 + t;          // B*65536 pixels
  int b = gid >> 16, pix = gid & 65535;
  for (int i = t; i < 4096; i += 256) M[i] = ws[WF2_OFF + (b << 12) + i];
  if (t < 64) { wsum[t] = ws[WSUM_OFF + t]; bf[t] = b_f[t]; gm[t] = gm_[t]; bt[t] = bt_[t]; }
  __syncthreads();
  const float* px = x2 + ((size_t)b << 22) + pix;
  float x[64];
#pragma unroll
  for (int c = 0; c < 64; ++c) x[c] = px[(size_t)c << 16];
  float spa = ws[SPA_OFF + gid];
  const float kbn = 0.99999500003749969f;  // 1/sqrt(1+1e-5)
  float* po = out + ((size_t)b << 22) + pix;
  for (int o = 0; o < 64; ++o) {
    float acc = fmaf(spa, wsum[o], bf[o]);
    const float* Mo = M + o * 64;
#pragma unroll
    for (int c = 0; c < 64; ++c) acc = fmaf(Mo[c], x[c], acc);
    float r = fmaf(acc * kbn, gm[o], bt[o]);
    po[(size_t)o << 16] = fmaxf(r, 0.f);
  }
}

extern "C" void kernel_launch(void* const* d_in, const int* in_sizes, int n_in,
                              void* d_out, int out_size, void* d_ws, size_t ws_size,
                              hipStream_t stream) {
  const float* x1   = (const float*)d_in[0];
  const float* x2   = (const float*)d_in[1];
  const float* w_c1 = (const float*)d_in[2];
  const float* b_c1 = (const float*)d_in[3];
  const float* w_c2 = (const float*)d_in[4];
  const float* b_c2 = (const float*)d_in[5];
  const float* w_p1 = (const float*)d_in[6];
  const float* b_p1 = (const float*)d_in[7];
  const float* w_p2 = (const float*)d_in[8];
  const float* b_p2 = (const float*)d_in[9];
  const float* w_lin= (const float*)d_in[10];
  const float* b_lin= (const float*)d_in[11];
  const float* w_f  = (const float*)d_in[12];
  const float* b_f  = (const float*)d_in[13];
  const float* gmm  = (const float*)d_in[14];
  const float* btt  = (const float*)d_in[15];
  float* ws  = (float*)d_ws;
  float* out = (float*)d_out;

  hipLaunchKernelGGL(k_gap,   dim3(768),  dim3(256), 0, stream, x1, x2, ws);
  hipLaunchKernelGGL(k_small, dim3(1),    dim3(256), 0, stream, w_c1, b_c1, w_c2, b_c2, w_f, ws);
  hipLaunchKernelGGL(k_pos,   dim3(1280), dim3(256), 0, stream, x1, x2, w_p1, b_p1, w_p2, b_p2, ws);
  hipLaunchKernelGGL(k_attn,  dim3(1024), dim3(256), 0, stream, w_lin, b_lin, ws);
  hipLaunchKernelGGL(k_final, dim3(1024), dim3(256), 0, stream, x2, b_f, gmm, btt, ws, out);
}